// Round 11
// baseline (39.967 us; speedup 1.0000x reference)
//
#include <hip/hip_runtime.h>

// CTC forward loss, B=512, T=512 (Tp=510 after [:,2:,:]), C=96, L=64, S=129.
// Round 11 = round-10 design with (a) preprocessor paste fix (token "0.s0")
// and (b) ds_bpermute replaced by a second chained DPP for O[l-2] (cheaper,
// and auto-zeroes lanes 0/1 -> no inf*0 NaN hazard).
// 2-step FUSION of the validated per-lane scaled-linear DP (r5/r8/r9
// evidence: wall = serial chain, not operand delivery / issue):
//   step t:   E1=(E+aO)*pb1 ; O1=(O+E+skipM*aO)*pl1
//   neighbor: O1n = (aO + aE + skipP*aO2) * (p[t][labPrev]+EPS)  == O1[l-1]
//             (computed in lane-l frame; aO,aE via DPP shr1; aO2 via DPP
//              shr1 twice; alignment d=e[l-1]-e[l], d2=e[l-2]-e[l] are EXACT
//              between renorms because steady steps never mutate e)
//   step t+1: E2=(E1+O1n)*pb2 ; O2=(O1+E1+skipM*O1n)*pl2
// Fill phase (t<=64) + guarded tails use the r8-validated robust stepF.
// Renorm cadence: every 4 t (validated; growth<=3^4, floor>=2^-93 normal).
// log-softmax normalizer: sum_c(p+EPS) == 1 + C*EPS exactly -> constant.

constexpr int   T_    = 512;
constexpr int   C_    = 96;
constexpr int   L_    = 64;
constexpr int   TP_   = 510;          // T - 2
constexpr float EPS_  = 1e-7f;
constexpr float LN2_  = 0.69314718055994530942f;
constexpr float LSE1_ = 1.3849806e-5f;   // log2(1 + C_*EPS_)

typedef float f8 __attribute__((ext_vector_type(8)));
typedef float f2 __attribute__((ext_vector_type(2)));

__device__ __forceinline__ float flog2(float x) {
#if __has_builtin(__builtin_amdgcn_logf)
  return __builtin_amdgcn_logf(x);
#else
  return log2f(x);
#endif
}
__device__ __forceinline__ float fexp2(float x) {
#if __has_builtin(__builtin_amdgcn_exp2f)
  return __builtin_amdgcn_exp2f(x);
#else
  return exp2f(x);
#endif
}
__device__ __forceinline__ float fldexp(float x, int n) {
#if __has_builtin(__builtin_amdgcn_ldexpf)
  return __builtin_amdgcn_ldexpf(x, n);
#else
  return __builtin_ldexpf(x, n);
#endif
}

template<int CTRL, int RM, int BM, bool BC>
__device__ __forceinline__ float dppf(float old_, float src) {
  return __int_as_float(__builtin_amdgcn_update_dpp(
      __float_as_int(old_), __float_as_int(src), CTRL, RM, BM, BC));
}
template<int CTRL, int RM, int BM, bool BC>
__device__ __forceinline__ int dppi(int old_, int src) {
  return __builtin_amdgcn_update_dpp(old_, src, CTRL, RM, BM, BC);
}

// log2(2^x + 2^y) — readout only
__device__ __forceinline__ float lae2(float x, float y) {
  float m = fmaxf(x, y);
  return m + flog2(1.f + fexp2(-fabsf(x - y)));
}

// ---- ring loads: literal element names only (SROA-safe, validated) ----
#define LOADF8(R, BASE, T0) { const float* _p = (BASE) + (size_t)(T0) * C_;  \
  R .s0=_p[0];    R .s1=_p[C_];   R .s2=_p[2*C_]; R .s3=_p[3*C_];            \
  R .s4=_p[4*C_]; R .s5=_p[5*C_]; R .s6=_p[6*C_]; R .s7=_p[7*C_]; }

#define LOADPP(R, T0) { const float* _p = colP + (size_t)(T0) * C_;          \
  R .s0=_p[0];     R .s1=_p[2*C_];  R .s2=_p[4*C_];  R .s3=_p[6*C_];         \
  R .s4=_p[8*C_];  R .s5=_p[10*C_]; R .s6=_p[12*C_]; R .s7=_p[14*C_]; }

#define LD1C(R, BASE, T0, J) { int _t = (T0) + (J);                          \
  _t = _t < TP_ ? _t : TP_ - 1; R .s##J = (BASE)[(size_t)_t * C_]; }
#define LOADF8C(R, BASE, T0)                                                 \
  LD1C(R,BASE,T0,0) LD1C(R,BASE,T0,1) LD1C(R,BASE,T0,2) LD1C(R,BASE,T0,3)    \
  LD1C(R,BASE,T0,4) LD1C(R,BASE,T0,5) LD1C(R,BASE,T0,6) LD1C(R,BASE,T0,7)
#define LP1C(R, T0, J) { int _t = (T0) + 2*(J);                              \
  _t = _t < TP_ ? _t : TP_ - 1; R .s##J = colP[(size_t)_t * C_]; }
#define LOADPPC(R, T0)                                                       \
  LP1C(R,T0,0) LP1C(R,T0,1) LP1C(R,T0,2) LP1C(R,T0,3)                        \
  LP1C(R,T0,4) LP1C(R,T0,5) LP1C(R,T0,6) LP1C(R,T0,7)

#define REFILL_H1(BK, T0) { LOADF8(PL##BK##0, colL, T0)                      \
                            LOADF8(PB##BK##0, colB, T0) }
#define REFILL_H2(BK, T0) { LOADF8(PL##BK##1, colL, (T0)+8)                  \
                            LOADF8(PB##BK##1, colB, (T0)+8)                  \
                            LOADPP(PP##BK, T0) }
#define REFILLC(BK, T0)   { LOADF8C(PL##BK##0, colL, T0)                     \
                            LOADF8C(PB##BK##0, colB, T0)                     \
                            LOADF8C(PL##BK##1, colL, (T0)+8)                 \
                            LOADF8C(PB##BK##1, colB, (T0)+8) }

// fused pair: consumes (pl1,pb1) at t, (pl2,pb2) at t+1, pp = p[t][labPrev]
#define FPAIR(PL1V, PB1V, PL2V, PB2V, PPV) {                                 \
  float pb1E = (PB1V) + EPS_, pl1E = (PL1V) + EPS_;                          \
  float pb2E = (PB2V) + EPS_, pl2E = (PL2V) + EPS_;                          \
  float ppE  = (PPV) + EPS_;                                                 \
  float mO1s = dppf<0x138, 0xf, 0xf, false>(0.f, mm.y);   /* m_O[l-1] */     \
  float mE1s = dppf<0x138, 0xf, 0xf, false>(0.f, mm.x);   /* m_E[l-1] */     \
  float mO2s = dppf<0x138, 0xf, 0xf, false>(0.f, mO1s);   /* m_O[l-2] */     \
  float aO   = fldexp(mO1s, d);                                              \
  float aE   = fldexp(mE1s, d);                                              \
  float aO2  = fldexp(mO2s, d2);                                             \
  float E1   = (mm.x + aO) * pb1E;                                           \
  float O1   = fmaf(aO, skipM, mm.y + mm.x) * pl1E;                          \
  float O1n  = fmaf(aO2, skipP, aO + aE) * ppE;                              \
  if constexpr (H128) { float X1 = (mX + mm.y) * pb1E;                       \
                        mX = (X1 + O1) * pb2E; }                             \
  float E2   = (E1 + O1n) * pb2E;                                            \
  float O2   = fmaf(O1n, skipM, O1 + E1) * pl2E;                             \
  mm.x = E2; mm.y = O2; }

// fused superblock: consume 16 t's (8 pairs) from bank BK, refill BK <- TNXT
#define FSB(BK, TNXT) {                                                      \
  FPAIR(PL##BK##0 .s0, PB##BK##0 .s0, PL##BK##0 .s1, PB##BK##0 .s1, PP##BK .s0) \
  FPAIR(PL##BK##0 .s2, PB##BK##0 .s2, PL##BK##0 .s3, PB##BK##0 .s3, PP##BK .s1) \
  renormS();                                                                 \
  FPAIR(PL##BK##0 .s4, PB##BK##0 .s4, PL##BK##0 .s5, PB##BK##0 .s5, PP##BK .s2) \
  FPAIR(PL##BK##0 .s6, PB##BK##0 .s6, PL##BK##0 .s7, PB##BK##0 .s7, PP##BK .s3) \
  renormS();                                                                 \
  REFILL_H1(BK, TNXT)                                                        \
  FPAIR(PL##BK##1 .s0, PB##BK##1 .s0, PL##BK##1 .s1, PB##BK##1 .s1, PP##BK .s4) \
  FPAIR(PL##BK##1 .s2, PB##BK##1 .s2, PL##BK##1 .s3, PB##BK##1 .s3, PP##BK .s5) \
  renormS();                                                                 \
  FPAIR(PL##BK##1 .s4, PB##BK##1 .s4, PL##BK##1 .s5, PB##BK##1 .s5, PP##BK .s6) \
  FPAIR(PL##BK##1 .s6, PB##BK##1 .s6, PL##BK##1 .s7, PB##BK##1 .s7, PP##BK .s7) \
  renormS();                                                                 \
  REFILL_H2(BK, TNXT) }

// fill superblock: 16 robust stepF from bank BK, refill BK <- TNXT
#define FILLSB(BK, TNXT) {                                                   \
  stepF(PL##BK##0 .s0, PB##BK##0 .s0); stepF(PL##BK##0 .s1, PB##BK##0 .s1);  \
  stepF(PL##BK##0 .s2, PB##BK##0 .s2); stepF(PL##BK##0 .s3, PB##BK##0 .s3);  \
  stepF(PL##BK##0 .s4, PB##BK##0 .s4); stepF(PL##BK##0 .s5, PB##BK##0 .s5);  \
  stepF(PL##BK##0 .s6, PB##BK##0 .s6); stepF(PL##BK##0 .s7, PB##BK##0 .s7);  \
  REFILL_H1(BK, TNXT)                                                        \
  stepF(PL##BK##1 .s0, PB##BK##1 .s0); stepF(PL##BK##1 .s1, PB##BK##1 .s1);  \
  stepF(PL##BK##1 .s2, PB##BK##1 .s2); stepF(PL##BK##1 .s3, PB##BK##1 .s3);  \
  stepF(PL##BK##1 .s4, PB##BK##1 .s4); stepF(PL##BK##1 .s5, PB##BK##1 .s5);  \
  stepF(PL##BK##1 .s6, PB##BK##1 .s6); stepF(PL##BK##1 .s7, PB##BK##1 .s7);  \
  REFILL_H2(BK, TNXT) }

#define G1(BK, HF, T0, J)                                                    \
  if ((T0) + (J) < tmax) stepF(PL##BK##HF .s##J, PB##BK##HF .s##J);
#define GUARD16(BK, T0) {                                                    \
  G1(BK,0,T0,0) G1(BK,0,T0,1) G1(BK,0,T0,2) G1(BK,0,T0,3)                    \
  G1(BK,0,T0,4) G1(BK,0,T0,5) G1(BK,0,T0,6) G1(BK,0,T0,7)                    \
  { const int _u0 = (T0) + 8;                                                \
    G1(BK,1,_u0,0) G1(BK,1,_u0,1) G1(BK,1,_u0,2) G1(BK,1,_u0,3)              \
    G1(BK,1,_u0,4) G1(BK,1,_u0,5) G1(BK,1,_u0,6) G1(BK,1,_u0,7) } }

// guarded 64-step tail from banks B1 (tb..+15), B2 (tb+16..+31), refills
#define TAILX(B1, B2) {                                                      \
  GUARD16(B1, tb)                                                            \
  REFILLC(B1, tb + 32)                                                       \
  GUARD16(B2, tb + 16)                                                       \
  REFILLC(B2, tb + 48)                                                       \
  GUARD16(B1, tb + 32)                                                       \
  GUARD16(B2, tb + 48) }

__global__ __launch_bounds__(64, 1) void ctc_fwd(
    const int* __restrict__ y_true, const float* __restrict__ y_pred,
    const int* __restrict__ input_len, const int* __restrict__ label_len,
    float* __restrict__ out)
{
  const int b = blockIdx.x;
  const int l = threadIdx.x;   // 0..63

  const float* __restrict__ rp = y_pred + (size_t)b * T_ * C_ + 2 * C_;
  const int  lab     = y_true[b * L_ + l];        // label of odd state 2l+1
  const int  labPrev = __shfl_up(lab, 1);
  const float skipM  = (l >= 1 && lab != labPrev) ? 1.f : 0.f;
  const float skipP  = __shfl_up(skipM, 1);        // 0 at lanes 0,1
  const int  ilen    = input_len[b];
  const int  llen    = label_len[b];               // in [16, 64]
  const int  tmax    = ilen < TP_ ? ilen : TP_;    // 510 for this data

  const float* __restrict__ colL = rp + lab;       // own-label column
  const float* __restrict__ colP = rp + labPrev;   // prev-label column
  const float* __restrict__ colB = rp + (C_ - 1);  // blank column (uniform)

  // per-lane scaled-linear state: alpha = m * 2^e ; m = (mE, mO)
  f2    mm;
  float mX = 0.f;
  int   e = 0, d = 0, d2 = 0;
  mm.x = (l == 0) ? (colB[0] + EPS_) : 0.f;
  mm.y = (l == 0) ? (colL[0] + EPS_) : 0.f;

  // two 16-step banks x {pl, pb, pp}
  f8 PLa0, PLa1, PBa0, PBa1, PPa, PLb0, PLb1, PBb0, PBb1, PPb;
  LOADF8C(PLa0, colL, 1)  LOADF8C(PBa0, colB, 1)
  LOADF8C(PLa1, colL, 9)  LOADF8C(PBa1, colB, 9)   LOADPPC(PPa, 1)
  LOADF8C(PLb0, colL, 17) LOADF8C(PBb0, colB, 17)
  LOADF8C(PLb1, colL, 25) LOADF8C(PBb1, colB, 25)  LOADPPC(PPb, 17)

  auto runDP = [&](auto hasC) {
    constexpr bool H128 = decltype(hasC)::value;

    // robust step: per-step renorm + empty-lane exponent adoption (r8)
    auto stepF = [&](float pl, float pb) {
      float plE = pl + EPS_, pbE = pb + EPS_;
      int   en  = dppi<0x138, 0xf, 0xf, false>(0, e);      // wave_shr1
      float m1  = dppf<0x138, 0xf, 0xf, false>(0.f, mm.y);
      int   dd  = en - e;  dd = dd < 120 ? dd : 120;
      float a1  = fldexp(m1, dd);
      float nE  = (mm.x + a1) * pbE;
      float nO  = fmaf(a1, skipM, mm.y + mm.x) * plE;
      float nX = 0.f, mx;
      if constexpr (H128) { nX = (mX + mm.y) * pbE; mx = fmaxf(fmaxf(nE, nO), nX); }
      else                { mx = fmaxf(nE, nO); }
      int  kb = __float_as_int(mx) >> 23;
      int  ks = 127 - kb;
      bool z  = (mx == 0.f);
      e  = z ? en : (e + kb - 127);
      mm.x = fldexp(nE, ks);
      mm.y = fldexp(nO, ks);
      if constexpr (H128) mX = fldexp(nX, ks);
    };

    // steady renorm (all lanes nonzero): refresh e, d, d2
    auto renormS = [&]() {
      float mx = fmaxf(mm.x, mm.y);
      if constexpr (H128) mx = fmaxf(mx, mX);
      int kb = __float_as_int(mx) >> 23;   // mx > 0, normal in steady phase
      int ks = 127 - kb;
      e += kb - 127;
      mm.x = fldexp(mm.x, ks);
      mm.y = fldexp(mm.y, ks);
      if constexpr (H128) mX = fldexp(mX, ks);
      int en  = dppi<0x138, 0xf, 0xf, false>(0, e);    // e[l-1]
      int en2 = dppi<0x138, 0xf, 0xf, false>(0, en);   // e[l-2]
      int dd  = en  - e;  d  = dd  < 120 ? dd  : 120;
      int dd2 = en2 - e;  d2 = dd2 < 120 ? dd2 : 120;
    };

    int tb = 1;
    if (tmax >= 81) {
      // fill phase t = 1..64 (robust, unguarded; refills keep banks primed)
      FILLSB(a, 33) FILLSB(b, 49) FILLSB(a, 65) FILLSB(b, 81)
      tb = 65;
      renormS();
      // steady fused phase, 32 t per iteration (banks A then B)
#pragma unroll 1
      for (; tb + 64 <= tmax; ) {
        FSB(a, tb + 32) tb += 16;
        FSB(b, tb + 32) tb += 16;
      }
      if (tb + 48 <= tmax) {
        FSB(a, tb + 32) tb += 16;
        TAILX(b, a)
      } else {
        TAILX(a, b)
      }
    } else {
      // slow general path (never taken for this dataset: tmax == 510)
#pragma unroll 1
      for (int t = 1; t < tmax; ++t)
        stepF(colL[(size_t)t * C_], colB[(size_t)t * C_]);
    }
  };

  if (llen >= 64) runDP(std::integral_constant<bool, true>{});
  else            runDP(std::integral_constant<bool, false>{});

  // readout: log2(alpha) = log2(m) + e   (transcendentals only here)
  float ef  = (float)e;
  float lgE = flog2(mm.x) + ef;
  float lgO = flog2(mm.y) + ef;
  float aL;
  if (llen >= 64) { float lgX = flog2(mX) + ef; aL = __shfl(lgX, 63); }
  else            { aL = __shfl(lgE, llen); }
  float aP = __shfl(lgO, llen - 1);
  if (l == 0)
    out[b] = -LN2_ * (lae2(aL, aP) - (float)tmax * LSE1_);
}

extern "C" void kernel_launch(void* const* d_in, const int* in_sizes, int n_in,
                              void* d_out, int out_size, void* d_ws, size_t ws_size,
                              hipStream_t stream) {
  const int*   y_true = (const int*)d_in[0];
  const float* y_pred = (const float*)d_in[1];
  const int*   ilen   = (const int*)d_in[2];
  const int*   llen   = (const int*)d_in[3];
  float*       outp   = (float*)d_out;
  const int    B      = out_size;   // 512
  hipLaunchKernelGGL(ctc_fwd, dim3(B), dim3(64), 0, stream,
                     y_true, y_pred, ilen, llen, outp);
}